// Round 3
// baseline (646.609 us; speedup 1.0000x reference)
//
#include <hip/hip_runtime.h>

#define BB 1024
#define TT 512
#define KK 64

typedef float v2f __attribute__((ext_vector_type(2)));

// ---- wave(64)-wide reductions via butterfly shuffles (tails only) ----
__device__ __forceinline__ float wmaxf(float x) {
#pragma unroll
  for (int off = 32; off > 0; off >>= 1) x = fmaxf(x, __shfl_xor(x, off, 64));
  return x;
}
__device__ __forceinline__ float wsumf(float x) {
#pragma unroll
  for (int off = 32; off > 0; off >>= 1) x += __shfl_xor(x, off, 64);
  return x;
}

// One block = one batch element. 128 threads = 2 waves:
//   wave0: forward algorithm (logZ) + gold score -> nll = logZ - gold
//   wave1: viterbi recurrence (bp in LDS) + backtrace -> path
// Disjoint LDS buffers, no inter-wave sync.
extern "C" __global__ void __launch_bounds__(128, 2) crf_all_kernel(
    const float* __restrict__ em,      // [B,T,K]
    const int* __restrict__ tags,      // [B,T]
    const int* __restrict__ mask,      // [B,T]
    const float* __restrict__ trans,   // [K,K]
    const float* __restrict__ startt,  // [K]
    const float* __restrict__ endt,    // [K]
    float* __restrict__ out) {         // [B] nll ++ [B,T] path (as float)
  __shared__ unsigned char bp[(TT - 1) * KK];     // 32704 B backpointers
  __shared__ __align__(16) float pbuf[KK];        // forward exp(alpha-M)
  __shared__ __align__(16) float vbuf[KK];        // viterbi v broadcast

  const int b = blockIdx.x;
  const int lane = threadIdx.x & 63;
  const float* emb = em + (size_t)b * TT * KK;
  const int* maskb = mask + b * TT;
  const int* tagsb = tags + b * TT;

  // Pre-ballot 512 mask bits into 8 wave-uniform u64s: per-step mask is pure
  // scalar ALU, zero memory ops inside the recurrence loops.
  unsigned long long mb[8];
#pragma unroll
  for (int u = 0; u < 8; ++u) mb[u] = __ballot(maskb[u * KK + lane] != 0);

  if (threadIdx.x < 64) {
    // ---------------- wave0: forward (logZ) + gold score ----------------
    // lane j holds column j of E = exp(trans) as 32 float2 pairs (pk-math).
    v2f Ecol2[KK / 2];
#pragma unroll
    for (int q = 0; q < KK / 2; ++q) {
      Ecol2[q].x = __expf(trans[(2 * q + 0) * KK + lane]);
      Ecol2[q].y = __expf(trans[(2 * q + 1) * KK + lane]);
    }

    float alpha = startt[lane] + emb[lane];
    int t = 1;
#pragma unroll 1
    for (int u = 0; u < 8; ++u) {
      unsigned long long um = mb[u];
      int s = 0;
      if (u == 0) { um >>= 1; s = 1; }
#pragma unroll 1
      for (; s < 64; ++s, ++t) {
        const int m = (int)(um & 1ull);
        um >>= 1;
        float emv = emb[t * KK + lane];  // issued early, consumed at chain end
        // Stabilization point: ANY in-range M works (tolerance ~49 abs);
        // lane0's alpha avoids the 6-stage shuffle chain.
        float M = __int_as_float(__builtin_amdgcn_readfirstlane(__float_as_int(alpha)));
        pbuf[lane] = __expf(alpha - M);
        __builtin_amdgcn_wave_barrier();  // same-wave LDS in-order; fence compiler
        v2f s01 = {0.f, 0.f}, s23 = {0.f, 0.f};
        const float4* pb4 = (const float4*)pbuf;
#pragma unroll
        for (int q = 0; q < KK / 4; ++q) {
          float4 pv = pb4[q];  // same-address broadcast ds_read_b128
          s01 += (v2f){pv.x, pv.y} * Ecol2[2 * q + 0];  // v_pk_fma_f32
          s23 += (v2f){pv.z, pv.w} * Ecol2[2 * q + 1];
        }
        __builtin_amdgcn_wave_barrier();
        float ssum = (s01.x + s01.y) + (s23.x + s23.y);
        float na = __logf(ssum) + M + emv;
        alpha = (m != 0) ? na : alpha;
      }
    }
    // logZ = logsumexp(alpha + end) — exact max here (runs once)
    float x = alpha + endt[lane];
    float M2 = wmaxf(x);
    float S = wsumf(__expf(x - M2));
    float logZ = __logf(S) + M2;

    // gold score: lane j covers t = u*64 + j; mask from mb bits
    float acc = 0.f;
#pragma unroll
    for (int u = 0; u < TT / KK; ++u) {
      int t2 = u * KK + lane;
      int tg = tagsb[t2];
      float mf = (float)((mb[u] >> lane) & 1ull);
      acc = fmaf(emb[t2 * KK + tg], mf, acc);
      if (t2 >= 1) acc = fmaf(trans[tagsb[t2 - 1] * KK + tg], mf, acc);
    }
    acc = wsumf(acc);
    int msum = 0;
#pragma unroll
    for (int u = 0; u < 8; ++u) msum += __popcll(mb[u]);
    if (lane == 0) {
      float gold = acc + startt[tagsb[0]] + endt[tagsb[msum - 1]];
      out[b] = logZ - gold;
    }
  } else {
    // ---------------- wave1: viterbi + backtrace ----------------
    // lane j holds column j of trans as 32 float2 pairs.
    v2f Tcol2[KK / 2];
#pragma unroll
    for (int q = 0; q < KK / 2; ++q) {
      Tcol2[q].x = trans[(2 * q + 0) * KK + lane];
      Tcol2[q].y = trans[(2 * q + 1) * KK + lane];
    }

    float v = startt[lane] + emb[lane];
    int t = 1;
#pragma unroll 1
    for (int u = 0; u < 8; ++u) {
      unsigned long long um = mb[u];
      int s = 0;
      if (u == 0) { um >>= 1; s = 1; }
#pragma unroll 1
      for (; s < 64; ++s, ++t) {
        const int m = (int)(um & 1ull);
        um >>= 1;
        float emv = emb[t * KK + lane];
        vbuf[lane] = v;
        __builtin_amdgcn_wave_barrier();
        const float4* vb4 = (const float4*)vbuf;
        // 4 chunks of 16; within each chunk a pairwise tournament (depth 4),
        // then a running merge. Left-wins-on-'>=' at every level ==
        // np.argmax first-index tie-break; fmaxf value path is exact, so
        // nv = best + em bit-matches the reference recurrence.
        float bv = 0.f; int bx = 0;
#pragma unroll
        for (int ch = 0; ch < 4; ++ch) {
          const int base = ch * 16;
          float cv[16];
#pragma unroll
          for (int q = 0; q < 4; ++q) {
            float4 pv = vb4[ch * 4 + q];  // broadcast ds_read_b128
            v2f lo = (v2f){pv.x, pv.y} + Tcol2[ch * 8 + 2 * q + 0];  // v_pk_add_f32
            v2f hi = (v2f){pv.z, pv.w} + Tcol2[ch * 8 + 2 * q + 1];
            cv[4 * q + 0] = lo.x; cv[4 * q + 1] = lo.y;
            cv[4 * q + 2] = hi.x; cv[4 * q + 3] = hi.y;
          }
          float m8[8]; int i8[8];
#pragma unroll
          for (int q = 0; q < 8; ++q) {
            m8[q] = fmaxf(cv[2 * q], cv[2 * q + 1]);
            i8[q] = (cv[2 * q] >= cv[2 * q + 1]) ? (base + 2 * q) : (base + 2 * q + 1);
          }
          float m4[4]; int i4[4];
#pragma unroll
          for (int q = 0; q < 4; ++q) {
            m4[q] = fmaxf(m8[2 * q], m8[2 * q + 1]);
            i4[q] = (m8[2 * q] >= m8[2 * q + 1]) ? i8[2 * q] : i8[2 * q + 1];
          }
          float m2a = fmaxf(m4[0], m4[1]);
          int i2a = (m4[0] >= m4[1]) ? i4[0] : i4[1];
          float m2b = fmaxf(m4[2], m4[3]);
          int i2b = (m4[2] >= m4[3]) ? i4[2] : i4[3];
          float cm = fmaxf(m2a, m2b);
          int ci = (m2a >= m2b) ? i2a : i2b;
          if (ch == 0) { bv = cm; bx = ci; }
          else { bx = (bv >= cm) ? bx : ci; bv = fmaxf(bv, cm); }
        }
        __builtin_amdgcn_wave_barrier();
        bp[(t - 1) * KK + lane] = (unsigned char)((m != 0) ? bx : lane);
        v = (m != 0) ? (bv + emv) : v;
      }
    }
    // last = argmax(v + end), first-index on exact ties
    float sc = v + endt[lane];
    int idx = lane;
#pragma unroll
    for (int off = 32; off > 0; off >>= 1) {
      float osc = __shfl_xor(sc, off, 64);
      int oidx = __shfl_xor(idx, off, 64);
      if (osc > sc || (osc == sc && oidx < idx)) { sc = osc; idx = oidx; }
    }
    // backtrace: uniform LDS pointer chase
    int tag = idx;
    float* pout = out + BB + (size_t)b * TT;
    for (int tt = TT - 1; tt >= 1; --tt) {
      if (lane == 0) pout[tt] = (float)tag;
      tag = bp[(tt - 1) * KK + tag];
    }
    if (lane == 0) pout[0] = (float)tag;
  }
}

extern "C" void kernel_launch(void* const* d_in, const int* in_sizes, int n_in,
                              void* d_out, int out_size, void* d_ws, size_t ws_size,
                              hipStream_t stream) {
  (void)in_sizes; (void)n_in; (void)out_size; (void)d_ws; (void)ws_size;
  const float* em = (const float*)d_in[0];
  const int* tags = (const int*)d_in[1];
  const int* mask = (const int*)d_in[2];
  const float* trans = (const float*)d_in[3];
  const float* startt = (const float*)d_in[4];
  const float* endt = (const float*)d_in[5];
  float* out = (float*)d_out;
  crf_all_kernel<<<dim3(BB), dim3(128), 0, stream>>>(em, tags, mask, trans,
                                                     startt, endt, out);
}